// Round 5
// baseline (282.145 us; speedup 1.0000x reference)
//
#include <hip/hip_runtime.h>
#include <hip/hip_cooperative_groups.h>
#include <math.h>

// Disable FP contraction globally: selection thresholds (iou >= 0.5) must be
// bit-exact vs the numpy float32 reference; FMA rewrites would perturb them.
#pragma clang fp contract(off)

namespace cg = cooperative_groups;

#define BN     16      // batch
#define NP     2000    // proposals per batch
#define NG     200     // gt boxes per batch
#define NT     200     // output slots (T)
#define PMAX   66      // int(T * 0.33)
#define EPSF   1e-6f
#define MH     28
#define MW     28
#define HM     56      // input mask H=W
#define NPIX   (HM*HM) // 3136
#define NPLANE 66      // max distinct assigned GTs per batch (<= PMAX)
#define NBLK   256     // cooperative grid: one block per CU

// LDS overlay (union of per-phase layouts), 16 B aligned:
//  Phase A: gbox float4[200] @0 (3200) | garea float[200] @3200 (800)
//           | gflag int[200] @4000 (800)
//  Phase B: pos_list u16[2000] @0 (4000) | neg_list u16[2000] @4000 (4000)
//           | used int[200] @8000 (800) | gplane int[200] @8800 (800)
//  Phase G: tile float[64][204] @0 (52224) | glist u16[200] @52224 (400)
#define SMEM_BYTES 52640

// ---------------------------------------------------------------------------
// Fused cooperative kernel: A (IoU/flags) -> B (compaction/slots) ->
// G (mask transpose) -> C (bilinear crop). grid.sync() between phases.
// All phase logic identical to the R4 4-kernel version.
// ---------------------------------------------------------------------------
__global__ __launch_bounds__(256) void kFused(
    const float* __restrict__ proposals, const int* __restrict__ cls_ids,
    const float* __restrict__ boxes, const float* __restrict__ masks,
    float* __restrict__ out,
    int* __restrict__ flag_ws, int* __restrict__ assign_ws,
    float* __restrict__ mm_ws, int* __restrict__ pa_ws,
    int* __restrict__ gmap_ws, int* __restrict__ ucount_ws,
    float* __restrict__ staged)
{
#pragma clang fp contract(off)
  __shared__ __align__(16) char smem[SMEM_BYTES];
  __shared__ int wcp[4], wcn[4], wtot[4];
  __shared__ int s_pt, s_nt;

  cg::grid_group grid = cg::this_grid();
  const int tid  = threadIdx.x;
  const int lane = tid & 63;
  const int wv   = tid >> 6;
  const int blk  = blockIdx.x;

  // ========================= Phase A =========================
  // 128 units = 16 batches x 8 chunks of 256 proposals.
  if (blk < BN * 8) {
    const int b     = blk >> 3;
    const int chunk = blk & 7;
    float4* gbox = (float4*)smem;
    float*  garea = (float*)(smem + 3200);
    int*    gflag = (int*)(smem + 4000);

    if (tid < NG) {
      float4 g = reinterpret_cast<const float4*>(boxes + (size_t)b * NG * 4)[tid];
      int c = cls_ids[b * NG + tid];
      bool vg = (g.x != 0.f) || (g.y != 0.f) || (g.z != 0.f) || (g.w != 0.f);
      gbox[tid]  = g;
      garea[tid] = (g.z - g.x) * (g.w - g.y);
      gflag[tid] = vg ? (c > 0 ? 1 : (c < 0 ? 2 : 0)) : 0;
    }
    __syncthreads();

    int i = chunk * 256 + tid;
    if (i < NP) {
      float4 p = reinterpret_cast<const float4*>(proposals + (size_t)b * NP * 4)[i];
      bool vp = (p.x != 0.f) || (p.y != 0.f) || (p.z != 0.f) || (p.w != 0.f);
      if (!vp) {
        flag_ws[b * NP + i]   = 0;
        assign_ws[b * NP + i] = 0;
      } else {
        float pa = (p.z - p.x) * (p.w - p.y);
        float best = -3.0e38f;   // first iter always wins -> argmax-first
        int   bestj = 0;
        float cmax = 0.f;
        for (int j = 0; j < NG; ++j) {
          float4 g = gbox[j];
          float iy = fmaxf(fminf(p.z, g.z) - fmaxf(p.x, g.x), 0.f);
          float ix = fmaxf(fminf(p.w, g.w) - fmaxf(p.y, g.y), 0.f);
          float inter = iy * ix;
          float uni = (pa + garea[j]) - inter;
          float iou = inter / fmaxf(uni, EPSF);
          int fl = gflag[j];
          float v = (fl == 1) ? iou : -1.0f;     // ov_nc
          if (v > best) { best = v; bestj = j; } // strict > => first max
          if (fl == 2) cmax = fmaxf(cmax, iou);
        }
        bool pos = (best >= 0.5f);
        bool neg = (best < 0.5f) && (cmax < 0.001f);
        flag_ws[b * NP + i]   = pos ? 1 : (neg ? 2 : 0);
        assign_ws[b * NP + i] = bestj;
      }
    }
  }
  __threadfence();
  grid.sync();

  // ========================= Phase B =========================
  // 16 blocks, one per batch. Stable compaction + slot assembly + plane map.
  if (blk < BN) {
    const int b = blk;
    unsigned short* pos_list = (unsigned short*)smem;
    unsigned short* neg_list = (unsigned short*)(smem + 4000);
    int* used   = (int*)(smem + 8000);
    int* gplane = (int*)(smem + 8800);

    if (tid == 0) { s_pt = 0; s_nt = 0; }
    __syncthreads();

    const int* fb = flag_ws + b * NP;
    for (int base = 0; base < NP; base += 256) {
      int i = base + tid;
      int f = (i < NP) ? fb[i] : 0;
      bool isp = (f == 1), isn = (f == 2);
      unsigned long long bp = __ballot(isp);
      unsigned long long bn = __ballot(isn);
      __syncthreads();
      if (lane == 0) { wcp[wv] = __popcll(bp); wcn[wv] = __popcll(bn); }
      __syncthreads();
      int prep = __popcll(bp & ((1ull << lane) - 1ull));
      int pren = __popcll(bn & ((1ull << lane) - 1ull));
      int bpp = 0, bnn = 0, tp = 0, tn = 0;
      for (int w = 0; w < 4; ++w) {
        if (w < wv) { bpp += wcp[w]; bnn += wcn[w]; }
        tp += wcp[w]; tn += wcn[w];
      }
      int pt = s_pt, nt = s_nt;
      if (isp) pos_list[pt + bpp + prep] = (unsigned short)i;
      if (isn) neg_list[nt + bnn + pren] = (unsigned short)i;
      __syncthreads();
      if (tid == 0) { s_pt = pt + tp; s_nt = nt + tn; }
    }
    __syncthreads();

    int pos_total = s_pt, neg_total = s_nt;
    int pos_count = min(pos_total, PMAX);
    int neg_needed = (int)floorf((float)pos_count / 0.33f) - pos_count;
    int neg_count = min(min(neg_needed, neg_total), NT - pos_count);

    if (tid < NG) used[tid] = 0;
    __syncthreads();

    int ma = -1;
    if (tid < NT) {
      bool ispos = tid < pos_count;
      bool isneg = (!ispos) && (tid < pos_count + neg_count);
      float r0 = 0.f, r1 = 0.f, r2 = 0.f, r3 = 0.f;
      float d0 = 0.f, d1 = 0.f, d2 = 0.f, d3 = 0.f;
      float m0 = 0.f, m1 = 0.f, m2 = 0.f, m3 = 0.f;
      float clsf = 0.f;
      if (ispos || isneg) {
        int i = ispos ? (int)pos_list[tid] : (int)neg_list[tid - pos_count];
        float4 p = reinterpret_cast<const float4*>(proposals + (size_t)b * NP * 4)[i];
        r0 = p.x; r1 = p.y; r2 = p.z; r3 = p.w;
        if (ispos) {
          int a = assign_ws[b * NP + i];
          ma = a;
          used[a] = 1;              // benign race: all writers store 1
          float4 g = reinterpret_cast<const float4*>(boxes + (size_t)b * NG * 4)[a];
          float h  = fmaxf(r2 - r0, EPSF);
          float w  = fmaxf(r3 - r1, EPSF);
          float cy = r0 + 0.5f * h;
          float cx = r1 + 0.5f * w;
          float gh = fmaxf(g.z - g.x, EPSF);
          float gw = fmaxf(g.w - g.y, EPSF);
          float gcy = g.x + 0.5f * gh;
          float gcx = g.y + 0.5f * gw;
          d0 = ((gcy - cy) / h) / 0.1f;
          d1 = ((gcx - cx) / w) / 0.1f;
          d2 = logf(gh / h) / 0.2f;
          d3 = logf(gw / w) / 0.2f;
          m0 = (r0 - g.x) / gh;
          m1 = (r1 - g.y) / gw;
          m2 = (r2 - g.x) / gh;
          m3 = (r3 - g.y) / gw;
          clsf = (float)cls_ids[b * NG + a];
        }
      }
      int s = b * NT + tid;
      float* rois = out;                         // [BN*NT*4]
      float* cls  = out + BN * NT * 4;           // [BN*NT]
      float* dlt  = out + BN * NT * 4 + BN * NT; // [BN*NT*4]
      rois[s * 4 + 0] = r0; rois[s * 4 + 1] = r1;
      rois[s * 4 + 2] = r2; rois[s * 4 + 3] = r3;
      cls[s] = clsf;
      dlt[s * 4 + 0] = d0; dlt[s * 4 + 1] = d1;
      dlt[s * 4 + 2] = d2; dlt[s * 4 + 3] = d3;
      mm_ws[s * 4 + 0] = m0; mm_ws[s * 4 + 1] = m1;
      mm_ws[s * 4 + 2] = m2; mm_ws[s * 4 + 3] = m3;
    }
    __syncthreads();

    // Ballot-scan: rank used g's ascending -> plane id.
    {
      int j = tid;
      int u = (j < NG) ? used[j] : 0;
      unsigned long long m = __ballot(u != 0);
      int pre = __popcll(m & ((1ull << lane) - 1ull));
      if (lane == 0) wtot[wv] = __popcll(m);
      __syncthreads();
      int basep = 0;
      for (int w = 0; w < wv; ++w) basep += wtot[w];
      if (j < NG) {
        int pl = u ? (basep + pre) : -1;
        gplane[j] = pl;
        gmap_ws[b * NG + j] = pl;
      }
    }
    __syncthreads();

    if (tid == 0)
      ucount_ws[b] = wtot[0] + wtot[1] + wtot[2] + wtot[3];
    if (tid < NT)
      pa_ws[b * NT + tid] = (ma >= 0) ? gplane[ma] : -1;
  }
  __threadfence();
  grid.sync();

  // ========================= Phase G =========================
  // 784 units (16 batches x 49 pixel-chunks of 64), block-strided.
  {
    float (*tile)[204] = (float(*)[204])smem;   // 816 B rows, 16 B aligned
    unsigned short* glist = (unsigned short*)(smem + 52224);

    for (int u = blk; u < BN * 49; u += NBLK) {
      int b  = u / 49;
      int p0 = (u - b * 49) * 64;
      __syncthreads();                 // previous unit fully consumed tile
      if (tid < NG) {
        int pl = gmap_ws[b * NG + tid];
        if (pl >= 0) glist[pl] = (unsigned short)tid;
      }
      const int U = ucount_ws[b];      // wave-uniform

      // read: wave wv, iter r -> pixel row p0 + r*4 + wv (800 B via dwordx4)
      const float* mb = masks + (size_t)b * NPIX * NG;
      for (int r = 0; r < 16; ++r) {
        int pl = r * 4 + wv;
        if (lane < 50) {
          float4 v = *reinterpret_cast<const float4*>(
              mb + (size_t)(p0 + pl) * NG + lane * 4);
          *reinterpret_cast<float4*>(&tile[pl][lane * 4]) = v;
        }
      }
      __syncthreads();
      // write: used planes round-robined over waves; lanes span pixels
      for (int u2 = wv; u2 < U; u2 += 4) {
        int g = (int)glist[u2];
        staged[(size_t)(b * NPLANE + u2) * NPIX + p0 + lane] = tile[lane][g];
      }
    }
  }
  __threadfence();
  grid.sync();

  // ========================= Phase C =========================
  // 3200 slots, block-strided; thread q -> 4 consecutive pixels (same row).
  {
    const int q = tid;                 // float4 index, 196 active
    for (int s = blk; s < BN * NT; s += NBLK) {
      if (q >= (MH * MW) / 4) continue;
      float4* om = reinterpret_cast<float4*>(
          out + (size_t)(BN * NT * 9) + (size_t)s * (MH * MW));
      int pa = pa_ws[s];
      if (pa < 0) { om[q] = make_float4(0.f, 0.f, 0.f, 0.f); continue; }

      const int b = s / NT;
      float y1 = mm_ws[s * 4 + 0], x1 = mm_ws[s * 4 + 1];
      float y2 = mm_ws[s * 4 + 2], x2 = mm_ws[s * 4 + 3];
      float sy = (y2 - y1) * 55.0f / 27.0f;    // reference order
      float sx = (x2 - x1) * 55.0f / 27.0f;
      const float* mp = staged + (size_t)(b * NPLANE + pa) * NPIX;

      int px0 = q * 4;
      int my  = px0 / MW;
      float ys = y1 * 55.0f + (float)my * sy;
      float y0f = floorf(ys);
      float wy  = ys - y0f;
      int y0i = (int)fminf(fmaxf(y0f, 0.f), 55.f);
      int y1i = (int)fminf(fmaxf(y0f + 1.0f, 0.f), 55.f);
      bool oky = (ys >= 0.f) && (ys <= 55.f);
      const float* r0 = mp + y0i * HM;
      const float* r1 = mp + y1i * HM;

      float res[4];
      for (int k = 0; k < 4; ++k) {
        int mx = (px0 + k) - my * MW;
        float xs = x1 * 55.0f + (float)mx * sx;
        float x0f = floorf(xs);
        float wx  = xs - x0f;
        int x0i = (int)fminf(fmaxf(x0f, 0.f), 55.f);
        int x1i = (int)fminf(fmaxf(x0f + 1.0f, 0.f), 55.f);
        float v00 = r0[x0i], v01 = r0[x1i];
        float v10 = r1[x0i], v11 = r1[x1i];
        float val = (v00 * (1.f - wx) + v01 * wx) * (1.f - wy)
                  + (v10 * (1.f - wx) + v11 * wx) * wy;
        bool ok = oky && (xs >= 0.f) && (xs <= 55.f);
        res[k] = ok ? rintf(val) : 0.f;        // rintf = ties-even = np.round
      }
      om[q] = make_float4(res[0], res[1], res[2], res[3]);
    }
  }
}

// ---------------------------------------------------------------------------
extern "C" void kernel_launch(void* const* d_in, const int* in_sizes, int n_in,
                              void* d_out, int out_size, void* d_ws, size_t ws_size,
                              hipStream_t stream)
{
  const float* proposals = (const float*)d_in[0];   // (16,2000,4)
  const int*   cls_ids   = (const int*)d_in[1];     // (16,200)
  const float* boxes     = (const float*)d_in[2];   // (16,200,4)
  const float* masks     = (const float*)d_in[3];   // (16,56,56,200)
  float* out = (float*)d_out;

  char* ws = (char*)d_ws;
  int*   flag_ws   = (int*)ws;    ws += (size_t)BN * NP * sizeof(int);
  int*   assign_ws = (int*)ws;    ws += (size_t)BN * NP * sizeof(int);
  float* mm_ws     = (float*)ws;  ws += (size_t)BN * NT * 4 * sizeof(float);
  int*   pa_ws     = (int*)ws;    ws += (size_t)BN * NT * sizeof(int);
  int*   gmap_ws   = (int*)ws;    ws += (size_t)BN * NG * sizeof(int);
  int*   ucount_ws = (int*)ws;    ws += (size_t)BN * sizeof(int);
  float* staged    = (float*)ws;  // BN*NPLANE*NPIX floats = 13.2 MB

  void* args[] = {
    (void*)&proposals, (void*)&cls_ids, (void*)&boxes, (void*)&masks,
    (void*)&out, (void*)&flag_ws, (void*)&assign_ws, (void*)&mm_ws,
    (void*)&pa_ws, (void*)&gmap_ws, (void*)&ucount_ws, (void*)&staged
  };
  hipLaunchCooperativeKernel((const void*)kFused, dim3(NBLK), dim3(256),
                             args, 0, stream);
}

// Round 6
// 139.796 us; speedup vs baseline: 2.0183x; 2.0183x over previous
//
#include <hip/hip_runtime.h>
#include <math.h>

// Disable FP contraction globally: selection thresholds (iou >= 0.5) must be
// bit-exact vs the numpy float32 reference; FMA rewrites would perturb them.
#pragma clang fp contract(off)

#define BN     16      // batch
#define NP     2000    // proposals per batch
#define NG     200     // gt boxes per batch
#define NT     200     // output slots (T)
#define PMAX   66      // int(T * 0.33)
#define EPSF   1e-6f
#define MH     28
#define MW     28
#define HM     56      // input mask H=W
#define NPIX   (HM*HM) // 3136
#define NPLANE 66      // max distinct assigned GTs per batch (<= PMAX)

// ---------------------------------------------------------------------------
// Kernel A: per-proposal reductions over GTs. 2 proposals per thread to
// amortize the LDS reads in the 200-iter IoU loop (kA is LDS-issue bound).
// grid (ceil(NP/512), BN), block 256.
// ---------------------------------------------------------------------------
__global__ __launch_bounds__(256) void kA(
    const float* __restrict__ proposals, const int* __restrict__ cls_ids,
    const float* __restrict__ boxes,
    int* __restrict__ flag_ws, int* __restrict__ assign_ws)
{
#pragma clang fp contract(off)
  const int b = blockIdx.y;
  __shared__ float4 gbox[NG];
  __shared__ float  garea[NG];
  __shared__ int    gflag[NG];   // 1 non-crowd, 2 crowd, 0 neither

  for (int j = threadIdx.x; j < NG; j += 256) {
    float4 g = reinterpret_cast<const float4*>(boxes + (size_t)b * NG * 4)[j];
    int c = cls_ids[b * NG + j];
    bool vg = (g.x != 0.f) || (g.y != 0.f) || (g.z != 0.f) || (g.w != 0.f);
    gbox[j]  = g;
    garea[j] = (g.z - g.x) * (g.w - g.y);
    gflag[j] = vg ? (c > 0 ? 1 : (c < 0 ? 2 : 0)) : 0;
  }
  __syncthreads();

  const int i0 = blockIdx.x * 512 + threadIdx.x;   // always < NP (max 1791)
  const int i1 = i0 + 256;                         // may exceed NP-1
  const bool has1 = (i1 < NP);
  const float4* pb = reinterpret_cast<const float4*>(proposals + (size_t)b * NP * 4);

  float4 p0 = pb[i0];
  float4 p1 = has1 ? pb[i1] : make_float4(0.f, 0.f, 0.f, 0.f);
  bool vp0 = (p0.x != 0.f) || (p0.y != 0.f) || (p0.z != 0.f) || (p0.w != 0.f);
  bool vp1 = (p1.x != 0.f) || (p1.y != 0.f) || (p1.z != 0.f) || (p1.w != 0.f);
  float pa0 = (p0.z - p0.x) * (p0.w - p0.y);
  float pa1 = (p1.z - p1.x) * (p1.w - p1.y);

  float best0 = -3.0e38f, best1 = -3.0e38f;  // first iter wins -> argmax-first
  int   bj0 = 0, bj1 = 0;
  float cm0 = 0.f, cm1 = 0.f;
  if (vp0 || vp1) {
    for (int j = 0; j < NG; ++j) {
      float4 g = gbox[j];
      float ga = garea[j];
      int   fl = gflag[j];
      // proposal 0
      {
        float iy = fmaxf(fminf(p0.z, g.z) - fmaxf(p0.x, g.x), 0.f);
        float ix = fmaxf(fminf(p0.w, g.w) - fmaxf(p0.y, g.y), 0.f);
        float inter = iy * ix;
        float uni = (pa0 + ga) - inter;
        float iou = inter / fmaxf(uni, EPSF);
        float v = (fl == 1) ? iou : -1.0f;
        if (v > best0) { best0 = v; bj0 = j; }
        if (fl == 2) cm0 = fmaxf(cm0, iou);
      }
      // proposal 1
      {
        float iy = fmaxf(fminf(p1.z, g.z) - fmaxf(p1.x, g.x), 0.f);
        float ix = fmaxf(fminf(p1.w, g.w) - fmaxf(p1.y, g.y), 0.f);
        float inter = iy * ix;
        float uni = (pa1 + ga) - inter;
        float iou = inter / fmaxf(uni, EPSF);
        float v = (fl == 1) ? iou : -1.0f;
        if (v > best1) { best1 = v; bj1 = j; }
        if (fl == 2) cm1 = fmaxf(cm1, iou);
      }
    }
  }
  {
    bool pos = vp0 && (best0 >= 0.5f);
    bool neg = vp0 && (best0 < 0.5f) && (cm0 < 0.001f);
    flag_ws[b * NP + i0]   = pos ? 1 : (neg ? 2 : 0);
    assign_ws[b * NP + i0] = bj0;
  }
  if (has1) {
    bool pos = vp1 && (best1 >= 0.5f);
    bool neg = vp1 && (best1 < 0.5f) && (cm1 < 0.001f);
    flag_ws[b * NP + i1]   = pos ? 1 : (neg ? 2 : 0);
    assign_ws[b * NP + i1] = bj1;
  }
}

// ---------------------------------------------------------------------------
// Kernel B: stable compaction + slot assembly + distinct-GT plane map.
// grid BN, block 256.
// ---------------------------------------------------------------------------
__global__ __launch_bounds__(256) void kB(
    const float* __restrict__ proposals, const int* __restrict__ cls_ids,
    const float* __restrict__ boxes, const int* __restrict__ flag_ws,
    const int* __restrict__ assign_ws, float* __restrict__ out,
    float* __restrict__ mm_ws, int* __restrict__ pa_ws,
    int* __restrict__ gmap_ws, int* __restrict__ ucount_ws)
{
#pragma clang fp contract(off)
  const int b = blockIdx.x;
  const int tid = threadIdx.x;
  const int lane = tid & 63;
  const int wv = tid >> 6;

  __shared__ unsigned short pos_list[NP];
  __shared__ unsigned short neg_list[NP];
  __shared__ int wcp[4], wcn[4];
  __shared__ int s_pt, s_nt;
  __shared__ int used[NG];
  __shared__ int gplane[NG];
  __shared__ int wtot[4];
  if (tid == 0) { s_pt = 0; s_nt = 0; }
  __syncthreads();

  const int* fb = flag_ws + b * NP;
  for (int base = 0; base < NP; base += 256) {
    int i = base + tid;
    int f = (i < NP) ? fb[i] : 0;
    bool isp = (f == 1), isn = (f == 2);
    unsigned long long bp = __ballot(isp);
    unsigned long long bn = __ballot(isn);
    __syncthreads();
    if (lane == 0) { wcp[wv] = __popcll(bp); wcn[wv] = __popcll(bn); }
    __syncthreads();
    int prep = __popcll(bp & ((1ull << lane) - 1ull));
    int pren = __popcll(bn & ((1ull << lane) - 1ull));
    int bpp = 0, bnn = 0, tp = 0, tn = 0;
    for (int w = 0; w < 4; ++w) {
      if (w < wv) { bpp += wcp[w]; bnn += wcn[w]; }
      tp += wcp[w]; tn += wcn[w];
    }
    int pt = s_pt, nt = s_nt;
    if (isp) pos_list[pt + bpp + prep] = (unsigned short)i;
    if (isn) neg_list[nt + bnn + pren] = (unsigned short)i;
    __syncthreads();
    if (tid == 0) { s_pt = pt + tp; s_nt = nt + tn; }
  }
  __syncthreads();

  int pos_total = s_pt, neg_total = s_nt;
  int pos_count = min(pos_total, PMAX);
  int neg_needed = (int)floorf((float)pos_count / 0.33f) - pos_count;
  int neg_count = min(min(neg_needed, neg_total), NT - pos_count);

  for (int j = tid; j < NG; j += 256) used[j] = 0;
  __syncthreads();

  int ma = -1;                      // this slot's assigned gt (register)
  if (tid < NT) {
    bool ispos = tid < pos_count;
    bool isneg = (!ispos) && (tid < pos_count + neg_count);
    float r0 = 0.f, r1 = 0.f, r2 = 0.f, r3 = 0.f;
    float d0 = 0.f, d1 = 0.f, d2 = 0.f, d3 = 0.f;
    float m0 = 0.f, m1 = 0.f, m2 = 0.f, m3 = 0.f;
    float clsf = 0.f;
    if (ispos || isneg) {
      int i = ispos ? (int)pos_list[tid] : (int)neg_list[tid - pos_count];
      float4 p = reinterpret_cast<const float4*>(proposals + (size_t)b * NP * 4)[i];
      r0 = p.x; r1 = p.y; r2 = p.z; r3 = p.w;
      if (ispos) {
        int a = assign_ws[b * NP + i];
        ma = a;
        used[a] = 1;                // benign race: all writers store 1
        float4 g = reinterpret_cast<const float4*>(boxes + (size_t)b * NG * 4)[a];
        float h  = fmaxf(r2 - r0, EPSF);
        float w  = fmaxf(r3 - r1, EPSF);
        float cy = r0 + 0.5f * h;
        float cx = r1 + 0.5f * w;
        float gh = fmaxf(g.z - g.x, EPSF);
        float gw = fmaxf(g.w - g.y, EPSF);
        float gcy = g.x + 0.5f * gh;
        float gcx = g.y + 0.5f * gw;
        d0 = ((gcy - cy) / h) / 0.1f;
        d1 = ((gcx - cx) / w) / 0.1f;
        d2 = logf(gh / h) / 0.2f;
        d3 = logf(gw / w) / 0.2f;
        m0 = (r0 - g.x) / gh;
        m1 = (r1 - g.y) / gw;
        m2 = (r2 - g.x) / gh;
        m3 = (r3 - g.y) / gw;
        clsf = (float)cls_ids[b * NG + a];
      }
    }
    int s = b * NT + tid;
    float* rois = out;                         // [BN*NT*4]
    float* cls  = out + BN * NT * 4;           // [BN*NT]
    float* dlt  = out + BN * NT * 4 + BN * NT; // [BN*NT*4]
    rois[s * 4 + 0] = r0; rois[s * 4 + 1] = r1;
    rois[s * 4 + 2] = r2; rois[s * 4 + 3] = r3;
    cls[s] = clsf;
    dlt[s * 4 + 0] = d0; dlt[s * 4 + 1] = d1;
    dlt[s * 4 + 2] = d2; dlt[s * 4 + 3] = d3;
    mm_ws[s * 4 + 0] = m0; mm_ws[s * 4 + 1] = m1;
    mm_ws[s * 4 + 2] = m2; mm_ws[s * 4 + 3] = m3;
  }
  __syncthreads();

  // Ballot-scan: rank used g's ascending -> plane id (consistent with kG).
  {
    int j = tid;                               // NG=200 < 256, one pass
    int u = (j < NG) ? used[j] : 0;
    unsigned long long m = __ballot(u != 0);
    int pre = __popcll(m & ((1ull << lane) - 1ull));
    if (lane == 0) wtot[wv] = __popcll(m);
    __syncthreads();
    int basep = 0;
    for (int w = 0; w < wv; ++w) basep += wtot[w];
    if (j < NG) {
      int pl = u ? (basep + pre) : -1;
      gplane[j] = pl;
      gmap_ws[b * NG + j] = pl;
    }
  }
  __syncthreads();

  if (tid == 0)
    ucount_ws[b] = wtot[0] + wtot[1] + wtot[2] + wtot[3];
  if (tid < NT)
    pa_ws[b * NT + tid] = (ma >= 0) ? gplane[ma] : -1;
}

// ---------------------------------------------------------------------------
// Kernel G: row-streaming transpose of used GT masks into contiguous planes.
// grid (NPIX/64 = 49, BN), block 256 (4 waves).
// Read: one wave = one 800 B pixel-row via dwordx4 (50 lanes x 16 B).
// Write: per used plane (exact list), lanes span pixels -> 256 B stores.
// ---------------------------------------------------------------------------
__global__ __launch_bounds__(256) void kG(
    const float* __restrict__ masks, const int* __restrict__ gmap_ws,
    const int* __restrict__ ucount_ws, float* __restrict__ staged)
{
  const int b   = blockIdx.y;
  const int p0  = blockIdx.x * 64;
  const int tid = threadIdx.x;
  const int lane = tid & 63;
  const int wv   = tid >> 6;

  // stride 204 floats = 816 B: 16 B-aligned rows for b128 LDS writes
  __shared__ float tile[64][204];
  __shared__ unsigned short glist[NG];   // plane id -> g (rank order from kB)

  if (tid < NG) {
    int pl = gmap_ws[b * NG + tid];
    if (pl >= 0) glist[pl] = (unsigned short)tid;
  }
  const int U = ucount_ws[b];            // scalar (wave-uniform) load

  // read phase: wave wv, iter r -> pixel row p0 + r*4 + wv
  const float* mb = masks + (size_t)b * NPIX * NG;
  for (int r = 0; r < 16; ++r) {
    int pl = r * 4 + wv;
    if (lane < 50) {
      float4 v = *reinterpret_cast<const float4*>(
          mb + (size_t)(p0 + pl) * NG + lane * 4);
      *reinterpret_cast<float4*>(&tile[pl][lane * 4]) = v;
    }
  }
  __syncthreads();

  // write phase: used planes round-robined over waves; lanes span pixels
  for (int u = wv; u < U; u += 4) {
    int g = (int)glist[u];
    staged[(size_t)(b * NPLANE + u) * NPIX + p0 + lane] = tile[lane][g];
  }
}

// ---------------------------------------------------------------------------
// Kernel C: bilinear crop-resize from staged planes. grid BN*NT, block 256.
// Each active thread computes 4 consecutive pixels (same output row).
// ---------------------------------------------------------------------------
__global__ __launch_bounds__(256) void kC(
    const float* __restrict__ staged, const float* __restrict__ mm_ws,
    const int* __restrict__ pa_ws, float* __restrict__ out)
{
#pragma clang fp contract(off)
  const int s = blockIdx.x;                    // b*NT + t
  float4* om = reinterpret_cast<float4*>(
      out + (size_t)(BN * NT * 9) + (size_t)s * (MH * MW));
  const int q = threadIdx.x;                   // float4 index, 196 active
  if (q >= (MH * MW) / 4) return;
  int pa = pa_ws[s];
  if (pa < 0) { om[q] = make_float4(0.f, 0.f, 0.f, 0.f); return; }

  const int b = s / NT;
  float y1 = mm_ws[s * 4 + 0], x1 = mm_ws[s * 4 + 1];
  float y2 = mm_ws[s * 4 + 2], x2 = mm_ws[s * 4 + 3];
  float sy = (y2 - y1) * 55.0f / 27.0f;        // reference order
  float sx = (x2 - x1) * 55.0f / 27.0f;
  const float* mp = staged + (size_t)(b * NPLANE + pa) * NPIX;

  int px0 = q * 4;
  int my  = px0 / MW;                          // same row for all 4
  float ys = y1 * 55.0f + (float)my * sy;
  float y0f = floorf(ys);
  float wy  = ys - y0f;
  int y0i = (int)fminf(fmaxf(y0f, 0.f), 55.f);
  int y1i = (int)fminf(fmaxf(y0f + 1.0f, 0.f), 55.f);
  bool oky = (ys >= 0.f) && (ys <= 55.f);
  const float* r0 = mp + y0i * HM;
  const float* r1 = mp + y1i * HM;

  float res[4];
  for (int k = 0; k < 4; ++k) {
    int mx = (px0 + k) - my * MW;
    float xs = x1 * 55.0f + (float)mx * sx;
    float x0f = floorf(xs);
    float wx  = xs - x0f;
    int x0i = (int)fminf(fmaxf(x0f, 0.f), 55.f);
    int x1i = (int)fminf(fmaxf(x0f + 1.0f, 0.f), 55.f);
    float v00 = r0[x0i], v01 = r0[x1i];
    float v10 = r1[x0i], v11 = r1[x1i];
    float val = (v00 * (1.f - wx) + v01 * wx) * (1.f - wy)
              + (v10 * (1.f - wx) + v11 * wx) * wy;
    bool ok = oky && (xs >= 0.f) && (xs <= 55.f);
    res[k] = ok ? rintf(val) : 0.f;            // rintf = ties-even = np.round
  }
  om[q] = make_float4(res[0], res[1], res[2], res[3]);
}

// ---------------------------------------------------------------------------
extern "C" void kernel_launch(void* const* d_in, const int* in_sizes, int n_in,
                              void* d_out, int out_size, void* d_ws, size_t ws_size,
                              hipStream_t stream)
{
  const float* proposals = (const float*)d_in[0];   // (16,2000,4)
  const int*   cls_ids   = (const int*)d_in[1];     // (16,200)
  const float* boxes     = (const float*)d_in[2];   // (16,200,4)
  const float* masks     = (const float*)d_in[3];   // (16,56,56,200)
  float* out = (float*)d_out;

  char* ws = (char*)d_ws;
  int*   flag_ws   = (int*)ws;    ws += (size_t)BN * NP * sizeof(int);
  int*   assign_ws = (int*)ws;    ws += (size_t)BN * NP * sizeof(int);
  float* mm_ws     = (float*)ws;  ws += (size_t)BN * NT * 4 * sizeof(float);
  int*   pa_ws     = (int*)ws;    ws += (size_t)BN * NT * sizeof(int);
  int*   gmap_ws   = (int*)ws;    ws += (size_t)BN * NG * sizeof(int);
  int*   ucount_ws = (int*)ws;    ws += (size_t)BN * sizeof(int);
  float* staged    = (float*)ws;  // BN*NPLANE*NPIX floats = 13.2 MB

  dim3 gA((NP + 511) / 512, BN);
  kA<<<gA, 256, 0, stream>>>(proposals, cls_ids, boxes, flag_ws, assign_ws);
  kB<<<BN, 256, 0, stream>>>(proposals, cls_ids, boxes, flag_ws, assign_ws,
                             out, mm_ws, pa_ws, gmap_ws, ucount_ws);
  dim3 gG(NPIX / 64, BN);
  kG<<<gG, 256, 0, stream>>>(masks, gmap_ws, ucount_ws, staged);
  kC<<<BN * NT, 256, 0, stream>>>(staged, mm_ws, pa_ws, out);
}

// Round 7
// 129.847 us; speedup vs baseline: 2.1729x; 1.0766x over previous
//
#include <hip/hip_runtime.h>
#include <math.h>

// Disable FP contraction globally: selection thresholds (iou >= 0.5) must be
// bit-exact vs the numpy float32 reference; FMA rewrites would perturb them.
#pragma clang fp contract(off)

#define BN     16      // batch
#define NP     2000    // proposals per batch
#define NG     200     // gt boxes per batch
#define NT     200     // output slots (T)
#define PMAX   66      // int(T * 0.33)
#define EPSF   1e-6f
#define MH     28
#define MW     28
#define HM     56      // input mask H=W
#define NPIX   (HM*HM) // 3136
#define NPLANE 66      // max distinct assigned GTs per batch (<= PMAX)

// ---------------------------------------------------------------------------
// Kernel A: per-proposal reductions over GTs. 1 proposal/thread (the 2x
// unroll regressed: VALU-bound loop, halved block count on an under-filled
// grid — R6 post-mortem). grid (8, BN), block 256.
// ---------------------------------------------------------------------------
__global__ __launch_bounds__(256) void kA(
    const float* __restrict__ proposals, const int* __restrict__ cls_ids,
    const float* __restrict__ boxes,
    int* __restrict__ flag_ws, int* __restrict__ assign_ws)
{
#pragma clang fp contract(off)
  const int b = blockIdx.y;
  __shared__ float4 gbox[NG];
  __shared__ float  garea[NG];
  __shared__ int    gflag[NG];   // 1 non-crowd, 2 crowd, 0 neither

  for (int j = threadIdx.x; j < NG; j += 256) {
    float4 g = reinterpret_cast<const float4*>(boxes + (size_t)b * NG * 4)[j];
    int c = cls_ids[b * NG + j];
    bool vg = (g.x != 0.f) || (g.y != 0.f) || (g.z != 0.f) || (g.w != 0.f);
    gbox[j]  = g;
    garea[j] = (g.z - g.x) * (g.w - g.y);
    gflag[j] = vg ? (c > 0 ? 1 : (c < 0 ? 2 : 0)) : 0;
  }
  __syncthreads();

  int i = blockIdx.x * 256 + threadIdx.x;
  if (i >= NP) return;

  float4 p = reinterpret_cast<const float4*>(proposals + (size_t)b * NP * 4)[i];
  bool vp = (p.x != 0.f) || (p.y != 0.f) || (p.z != 0.f) || (p.w != 0.f);
  if (!vp) {                         // zero-padded proposals: flag 0, no loop
    flag_ws[b * NP + i] = 0;
    assign_ws[b * NP + i] = 0;       // never read for non-positives
    return;
  }
  float pa = (p.z - p.x) * (p.w - p.y);

  float best = -3.0e38f;   // first iteration always wins -> argmax-first
  int   bestj = 0;
  float cmax = 0.f;
  for (int j = 0; j < NG; ++j) {
    float4 g = gbox[j];
    float iy = fmaxf(fminf(p.z, g.z) - fmaxf(p.x, g.x), 0.f);
    float ix = fmaxf(fminf(p.w, g.w) - fmaxf(p.y, g.y), 0.f);
    float inter = iy * ix;
    float uni = (pa + garea[j]) - inter;
    float iou = inter / fmaxf(uni, EPSF);
    int fl = gflag[j];
    float v = (fl == 1) ? iou : -1.0f;           // ov_nc
    if (v > best) { best = v; bestj = j; }       // strict > => first max
    if (fl == 2) cmax = fmaxf(cmax, iou);
  }
  bool pos = (best >= 0.5f);
  bool neg = (best < 0.5f) && (cmax < 0.001f);
  flag_ws[b * NP + i]   = pos ? 1 : (neg ? 2 : 0);
  assign_ws[b * NP + i] = bestj;
}

// ---------------------------------------------------------------------------
// Kernel B: stable compaction + slot assembly + distinct-GT plane map.
// grid BN, block 256.
// ---------------------------------------------------------------------------
__global__ __launch_bounds__(256) void kB(
    const float* __restrict__ proposals, const int* __restrict__ cls_ids,
    const float* __restrict__ boxes, const int* __restrict__ flag_ws,
    const int* __restrict__ assign_ws, float* __restrict__ out,
    float* __restrict__ mm_ws, int* __restrict__ pa_ws,
    int* __restrict__ gmap_ws, int* __restrict__ ucount_ws)
{
#pragma clang fp contract(off)
  const int b = blockIdx.x;
  const int tid = threadIdx.x;
  const int lane = tid & 63;
  const int wv = tid >> 6;

  __shared__ unsigned short pos_list[NP];
  __shared__ unsigned short neg_list[NP];
  __shared__ int wcp[4], wcn[4];
  __shared__ int s_pt, s_nt;
  __shared__ int used[NG];
  __shared__ int gplane[NG];
  __shared__ int wtot[4];
  if (tid == 0) { s_pt = 0; s_nt = 0; }
  __syncthreads();

  const int* fb = flag_ws + b * NP;
  for (int base = 0; base < NP; base += 256) {
    int i = base + tid;
    int f = (i < NP) ? fb[i] : 0;
    bool isp = (f == 1), isn = (f == 2);
    unsigned long long bp = __ballot(isp);
    unsigned long long bn = __ballot(isn);
    __syncthreads();
    if (lane == 0) { wcp[wv] = __popcll(bp); wcn[wv] = __popcll(bn); }
    __syncthreads();
    int prep = __popcll(bp & ((1ull << lane) - 1ull));
    int pren = __popcll(bn & ((1ull << lane) - 1ull));
    int bpp = 0, bnn = 0, tp = 0, tn = 0;
    for (int w = 0; w < 4; ++w) {
      if (w < wv) { bpp += wcp[w]; bnn += wcn[w]; }
      tp += wcp[w]; tn += wcn[w];
    }
    int pt = s_pt, nt = s_nt;
    if (isp) pos_list[pt + bpp + prep] = (unsigned short)i;
    if (isn) neg_list[nt + bnn + pren] = (unsigned short)i;
    __syncthreads();
    if (tid == 0) { s_pt = pt + tp; s_nt = nt + tn; }
  }
  __syncthreads();

  int pos_total = s_pt, neg_total = s_nt;
  int pos_count = min(pos_total, PMAX);
  int neg_needed = (int)floorf((float)pos_count / 0.33f) - pos_count;
  int neg_count = min(min(neg_needed, neg_total), NT - pos_count);

  for (int j = tid; j < NG; j += 256) used[j] = 0;
  __syncthreads();

  int ma = -1;                      // this slot's assigned gt (register)
  if (tid < NT) {
    bool ispos = tid < pos_count;
    bool isneg = (!ispos) && (tid < pos_count + neg_count);
    float r0 = 0.f, r1 = 0.f, r2 = 0.f, r3 = 0.f;
    float d0 = 0.f, d1 = 0.f, d2 = 0.f, d3 = 0.f;
    float m0 = 0.f, m1 = 0.f, m2 = 0.f, m3 = 0.f;
    float clsf = 0.f;
    if (ispos || isneg) {
      int i = ispos ? (int)pos_list[tid] : (int)neg_list[tid - pos_count];
      float4 p = reinterpret_cast<const float4*>(proposals + (size_t)b * NP * 4)[i];
      r0 = p.x; r1 = p.y; r2 = p.z; r3 = p.w;
      if (ispos) {
        int a = assign_ws[b * NP + i];
        ma = a;
        used[a] = 1;                // benign race: all writers store 1
        float4 g = reinterpret_cast<const float4*>(boxes + (size_t)b * NG * 4)[a];
        float h  = fmaxf(r2 - r0, EPSF);
        float w  = fmaxf(r3 - r1, EPSF);
        float cy = r0 + 0.5f * h;
        float cx = r1 + 0.5f * w;
        float gh = fmaxf(g.z - g.x, EPSF);
        float gw = fmaxf(g.w - g.y, EPSF);
        float gcy = g.x + 0.5f * gh;
        float gcx = g.y + 0.5f * gw;
        d0 = ((gcy - cy) / h) / 0.1f;
        d1 = ((gcx - cx) / w) / 0.1f;
        d2 = logf(gh / h) / 0.2f;
        d3 = logf(gw / w) / 0.2f;
        m0 = (r0 - g.x) / gh;
        m1 = (r1 - g.y) / gw;
        m2 = (r2 - g.x) / gh;
        m3 = (r3 - g.y) / gw;
        clsf = (float)cls_ids[b * NG + a];
      }
    }
    int s = b * NT + tid;
    float* rois = out;                         // [BN*NT*4]
    float* cls  = out + BN * NT * 4;           // [BN*NT]
    float* dlt  = out + BN * NT * 4 + BN * NT; // [BN*NT*4]
    rois[s * 4 + 0] = r0; rois[s * 4 + 1] = r1;
    rois[s * 4 + 2] = r2; rois[s * 4 + 3] = r3;
    cls[s] = clsf;
    dlt[s * 4 + 0] = d0; dlt[s * 4 + 1] = d1;
    dlt[s * 4 + 2] = d2; dlt[s * 4 + 3] = d3;
    mm_ws[s * 4 + 0] = m0; mm_ws[s * 4 + 1] = m1;
    mm_ws[s * 4 + 2] = m2; mm_ws[s * 4 + 3] = m3;
  }
  __syncthreads();

  // Ballot-scan: rank used g's ascending -> plane id (consistent with kG).
  {
    int j = tid;                               // NG=200 < 256, one pass
    int u = (j < NG) ? used[j] : 0;
    unsigned long long m = __ballot(u != 0);
    int pre = __popcll(m & ((1ull << lane) - 1ull));
    if (lane == 0) wtot[wv] = __popcll(m);
    __syncthreads();
    int basep = 0;
    for (int w = 0; w < wv; ++w) basep += wtot[w];
    if (j < NG) {
      int pl = u ? (basep + pre) : -1;
      gplane[j] = pl;
      gmap_ws[b * NG + j] = pl;
    }
  }
  __syncthreads();

  if (tid == 0)
    ucount_ws[b] = wtot[0] + wtot[1] + wtot[2] + wtot[3];
  if (tid < NT)
    pa_ws[b * NT + tid] = (ma >= 0) ? gplane[ma] : -1;
}

// ---------------------------------------------------------------------------
// Kernel G: row-streaming transpose of used GT masks into contiguous planes.
// grid (NPIX/64 = 49, BN), block 256 (4 waves).
// Read: one wave = one 800 B pixel-row via dwordx4 (50 lanes x 16 B).
// Write: per used plane (exact list), lanes span pixels -> 256 B stores.
// ---------------------------------------------------------------------------
__global__ __launch_bounds__(256) void kG(
    const float* __restrict__ masks, const int* __restrict__ gmap_ws,
    const int* __restrict__ ucount_ws, float* __restrict__ staged)
{
  const int b   = blockIdx.y;
  const int p0  = blockIdx.x * 64;
  const int tid = threadIdx.x;
  const int lane = tid & 63;
  const int wv   = tid >> 6;

  // stride 204 floats = 816 B: 16 B-aligned rows for b128 LDS writes
  __shared__ float tile[64][204];
  __shared__ unsigned short glist[NG];   // plane id -> g (rank order from kB)

  if (tid < NG) {
    int pl = gmap_ws[b * NG + tid];
    if (pl >= 0) glist[pl] = (unsigned short)tid;
  }
  const int U = ucount_ws[b];            // scalar (wave-uniform) load

  // read phase: wave wv, iter r -> pixel row p0 + r*4 + wv
  const float* mb = masks + (size_t)b * NPIX * NG;
  for (int r = 0; r < 16; ++r) {
    int pl = r * 4 + wv;
    if (lane < 50) {
      float4 v = *reinterpret_cast<const float4*>(
          mb + (size_t)(p0 + pl) * NG + lane * 4);
      *reinterpret_cast<float4*>(&tile[pl][lane * 4]) = v;
    }
  }
  __syncthreads();

  // write phase: used planes round-robined over waves; lanes span pixels
  for (int u = wv; u < U; u += 4) {
    int g = (int)glist[u];
    staged[(size_t)(b * NPLANE + u) * NPIX + p0 + lane] = tile[lane][g];
  }
}

// ---------------------------------------------------------------------------
// Kernel C: bilinear crop-resize from staged planes. grid BN*NT, block 256.
// Each active thread computes 4 consecutive pixels (same output row).
// ---------------------------------------------------------------------------
__global__ __launch_bounds__(256) void kC(
    const float* __restrict__ staged, const float* __restrict__ mm_ws,
    const int* __restrict__ pa_ws, float* __restrict__ out)
{
#pragma clang fp contract(off)
  const int s = blockIdx.x;                    // b*NT + t
  float4* om = reinterpret_cast<float4*>(
      out + (size_t)(BN * NT * 9) + (size_t)s * (MH * MW));
  const int q = threadIdx.x;                   // float4 index, 196 active
  if (q >= (MH * MW) / 4) return;
  int pa = pa_ws[s];
  if (pa < 0) { om[q] = make_float4(0.f, 0.f, 0.f, 0.f); return; }

  const int b = s / NT;
  float y1 = mm_ws[s * 4 + 0], x1 = mm_ws[s * 4 + 1];
  float y2 = mm_ws[s * 4 + 2], x2 = mm_ws[s * 4 + 3];
  float sy = (y2 - y1) * 55.0f / 27.0f;        // reference order
  float sx = (x2 - x1) * 55.0f / 27.0f;
  const float* mp = staged + (size_t)(b * NPLANE + pa) * NPIX;

  int px0 = q * 4;
  int my  = px0 / MW;                          // same row for all 4
  float ys = y1 * 55.0f + (float)my * sy;
  float y0f = floorf(ys);
  float wy  = ys - y0f;
  int y0i = (int)fminf(fmaxf(y0f, 0.f), 55.f);
  int y1i = (int)fminf(fmaxf(y0f + 1.0f, 0.f), 55.f);
  bool oky = (ys >= 0.f) && (ys <= 55.f);
  const float* r0 = mp + y0i * HM;
  const float* r1 = mp + y1i * HM;

  float res[4];
  for (int k = 0; k < 4; ++k) {
    int mx = (px0 + k) - my * MW;
    float xs = x1 * 55.0f + (float)mx * sx;
    float x0f = floorf(xs);
    float wx  = xs - x0f;
    int x0i = (int)fminf(fmaxf(x0f, 0.f), 55.f);
    int x1i = (int)fminf(fmaxf(x0f + 1.0f, 0.f), 55.f);
    float v00 = r0[x0i], v01 = r0[x1i];
    float v10 = r1[x0i], v11 = r1[x1i];
    float val = (v00 * (1.f - wx) + v01 * wx) * (1.f - wy)
              + (v10 * (1.f - wx) + v11 * wx) * wy;
    bool ok = oky && (xs >= 0.f) && (xs <= 55.f);
    res[k] = ok ? rintf(val) : 0.f;            // rintf = ties-even = np.round
  }
  om[q] = make_float4(res[0], res[1], res[2], res[3]);
}

// ---------------------------------------------------------------------------
extern "C" void kernel_launch(void* const* d_in, const int* in_sizes, int n_in,
                              void* d_out, int out_size, void* d_ws, size_t ws_size,
                              hipStream_t stream)
{
  const float* proposals = (const float*)d_in[0];   // (16,2000,4)
  const int*   cls_ids   = (const int*)d_in[1];     // (16,200)
  const float* boxes     = (const float*)d_in[2];   // (16,200,4)
  const float* masks     = (const float*)d_in[3];   // (16,56,56,200)
  float* out = (float*)d_out;

  char* ws = (char*)d_ws;
  int*   flag_ws   = (int*)ws;    ws += (size_t)BN * NP * sizeof(int);
  int*   assign_ws = (int*)ws;    ws += (size_t)BN * NP * sizeof(int);
  float* mm_ws     = (float*)ws;  ws += (size_t)BN * NT * 4 * sizeof(float);
  int*   pa_ws     = (int*)ws;    ws += (size_t)BN * NT * sizeof(int);
  int*   gmap_ws   = (int*)ws;    ws += (size_t)BN * NG * sizeof(int);
  int*   ucount_ws = (int*)ws;    ws += (size_t)BN * sizeof(int);
  float* staged    = (float*)ws;  // BN*NPLANE*NPIX floats = 13.2 MB

  dim3 gA((NP + 255) / 256, BN);
  kA<<<gA, 256, 0, stream>>>(proposals, cls_ids, boxes, flag_ws, assign_ws);
  kB<<<BN, 256, 0, stream>>>(proposals, cls_ids, boxes, flag_ws, assign_ws,
                             out, mm_ws, pa_ws, gmap_ws, ucount_ws);
  dim3 gG(NPIX / 64, BN);
  kG<<<gG, 256, 0, stream>>>(masks, gmap_ws, ucount_ws, staged);
  kC<<<BN * NT, 256, 0, stream>>>(staged, mm_ws, pa_ws, out);
}